// Round 16
// baseline (612.164 us; speedup 1.0000x reference)
//
#include <hip/hip_runtime.h>
#include <hip/hip_bf16.h>
#include <math.h>

#define Bn   256
#define Tn   128
#define HID  64
#define MCn  30

typedef __attribute__((ext_vector_type(8))) short bf16x8;
typedef __attribute__((ext_vector_type(4))) float f32x4;

// ---------------------------------------------------------------------------
__device__ __forceinline__ float rcp_(float x) { return __builtin_amdgcn_rcpf(x); }
__device__ __forceinline__ float tanhf_(float x) {
    float e = __expf(-2.0f * x);
    return __builtin_fmaf(2.0f, rcp_(1.0f + e), -1.0f);
}
__device__ __forceinline__ float sigmoidf_(float x) {
    return rcp_(1.0f + __expf(-x));
}
__device__ __forceinline__ float softplusf_(float z) {
    float e = __expf(-fabsf(z));
    return fmaxf(z, 0.0f) + __logf(1.0f + e);
}
__device__ __forceinline__ unsigned short f2b(float f) {
    union { float f; unsigned u; } v; v.f = f;
    unsigned r = v.u + 0x7FFF + ((v.u >> 16) & 1);
    return (unsigned short)(r >> 16);
}
__device__ __forceinline__ unsigned pk2(float a, float b) {
    union { __hip_bfloat162 h2; unsigned u; } cv;
    cv.h2 = __float22bfloat162_rn(make_float2(a, b));
    return cv.u;
}

// ws images (unchanged from r11)
extern "C" __global__ __launch_bounds__(256)
void prep_kernel(const int* __restrict__ marks, const float* __restrict__ mask,
                 const float* __restrict__ emb, const float* __restrict__ fW0,
                 const float* __restrict__ fW1, const float* __restrict__ fW2,
                 const float* __restrict__ fb0, const float* __restrict__ fb1,
                 const float* __restrict__ fb2, const float* __restrict__ ftw,
                 const float* __restrict__ Wi, const float* __restrict__ W_ih,
                 const float* __restrict__ W_hh,
                 const float* __restrict__ b_ih, const float* __restrict__ b_hh,
                 float* __restrict__ gc, float* __restrict__ invd,
                 float* __restrict__ parv, unsigned short* __restrict__ parwb,
                 float* __restrict__ seqw1T, float* __restrict__ seqw2T,
                 float* __restrict__ whh260)
{
    __shared__ float red[4];
    const int blk = blockIdx.x, tid = threadIdx.x;
    if (blk < Bn) {
        const int mark = marks[blk * Tn + 1];
        const float* er = emb + mark * HID;
        const float* wr = W_ih + tid * 65 + 1;
        float acc = b_ih[tid] + b_hh[tid];
        #pragma unroll
        for (int k = 0; k < HID; k++) acc += er[k] * wr[k];
        gc[blk * 256 + tid] = acc;
    } else if (blk == Bn) {
        float s = 0.f;
        for (int i = tid; i < Bn * Tn; i += 256) s += mask[i];
        #pragma unroll
        for (int off = 32; off >= 1; off >>= 1) s += __shfl_xor(s, off, 64);
        if ((tid & 63) == 0) red[tid >> 6] = s;
        __syncthreads();
        if (tid == 0) invd[0] = 1.0f / (red[0] + red[1] + red[2] + red[3]);
    } else if (blk == Bn + 1) {
        if (tid < 128) {
            int l = tid >> 6, m = tid & 63;
            parv[tid]       = fb0[tid];
            parv[128 + tid] = fW0[(l * 65 + 64) * 64 + m];
            parv[256 + tid] = fb1[tid];
            int act = 32 * (1 - l);
            parv[384 + tid] = fb2[l * 128 + act + (m & 31) + 64 * (m >> 5)];
        }
        if (tid < 64) {
            int l = tid >> 5, i2 = tid & 31, act = 32 * (1 - l);
            parv[512 + tid] = ftw[l * 128 + act + i2];
            parv[576 + tid] = ftw[l * 128 + 64 + act + i2];
            parv[640 + tid] = Wi[tid];
            parv[704 + tid] = 0.f;
        }
    } else if (blk == Bn + 2) {
        for (int i = tid; i < 5120; i += 256) {
            int k = i % 40, m = (i / 40) & 63, l = i / 2560;
            float v = (k < 32) ? fW0[(l * 65 + 32 * l + k) * 64 + m] : 0.f;
            parwb[i] = f2b(v);
        }
    } else if (blk == Bn + 3) {
        for (int i = tid; i < 9216; i += 256) {
            int k = i % 72, m = (i / 72) & 63, l = i / 4608;
            float v = (k < 64) ? fW1[(l * 64 + k) * 64 + m] : 0.f;
            parwb[5120 + i] = f2b(v);
        }
    } else if (blk == Bn + 4) {
        for (int i = tid; i < 9216; i += 256) {
            int k = i % 72, m = (i / 72) & 63, l = i / 4608;
            int act = 32 * (1 - l);
            float v = (k < 64) ? fW2[(l * 64 + k) * 128 + act + (m & 31) + 64 * (m >> 5)] : 0.f;
            parwb[14336 + i] = f2b(v);
        }
    } else if (blk == Bn + 5) {
        for (int i = tid; i < 8704; i += 256) {
            int k = i % 68, j = (i / 68) & 63, l = i / 4352;
            seqw1T[i] = (k < 64) ? fW1[(l * 64 + k) * 64 + j] : 0.f;
        }
    } else if (blk == Bn + 6) {
        for (int i = tid; i < 8704; i += 256) {
            int k = i % 68, j = (i / 68) & 63, l = i / 4352;
            int act = 32 * (1 - l);
            seqw2T[i] = (k < 64) ?
                fW2[(l * 64 + k) * 128 + act + (j & 31) + 64 * (j >> 5)] : 0.f;
        }
    } else {
        for (int i = tid; i < 16640; i += 256) {
            int j = i / 260, rem = i % 260, k = rem >> 2, r = rem & 3;
            whh260[i] = (k < 64) ? W_hh[(r * 64 + j) * 64 + k] : 0.f;
        }
    }
}

// ---------------------------------------------------------------------------
// FUSED kernel, FLAG-SYNCED (r15 champion) + LEAN PRODUCER: 4-slot hbuf/h2buf
// rings; producer has zero global ops and zero reductions in its loop; the
// h2 global flush lives on consumer wave 1 and the nll butterfly on consumer
// wave 2, both one step behind via the h2 ring. Back-pressure flg >= t-2 at
// producer step t covers both ring reuses (hbuf needs done(t-4), h2 needs
// done(t-3)).
extern "C" __global__ __launch_bounds__(192, 1)
void fused_kernel(const float* __restrict__ times, const float* __restrict__ mask,
                  const float* __restrict__ u,
                  const float* __restrict__ fW0, const float* __restrict__ fb0,
                  const float* __restrict__ fb1, const float* __restrict__ fb2,
                  const float* __restrict__ ftw, const float* __restrict__ Wi,
                  const float* __restrict__ bi, const float* __restrict__ W_ih,
                  const float* __restrict__ gc, const float* __restrict__ seqw1T,
                  const float* __restrict__ parv,
                  const unsigned short* __restrict__ parwb,
                  const float* __restrict__ invd, float* __restrict__ out)
{
    const int tid  = threadIdx.x;
    const int lane = tid & 63;
    const int w    = tid >> 6;       // 0=producer, 1..2=consumers
    const int b    = blockIdx.x;
    const int quad = lane >> 4, l15 = lane & 15;

    extern __shared__ float smem[];
    float* w1l   = smem;              //  8704 : w1T, stride 68
    float* w2l   = smem + 8704;       //  8704 : w2T, stride 68
    float* whhl  = smem + 17408;      // 16640 : whh260
    float* tl    = smem + 34048;      //   128
    float* ml    = smem + 34176;      //   128
    float* xl    = smem + 34304;      //    64 (producer-private)
    float* al    = smem + 34368;      //    64
    float* ssl   = smem + 34432;      //    64
    float* hbuf  = smem + 34496;      //   256 = 4 slots x 64
    float* h2buf = smem + 34752;      //   256 = 4 slots x 64
    float* pr    = smem + 35008;      //     4
    volatile unsigned* flg = (volatile unsigned*)(smem + 35012);  // [0]=prod,[1],[2]=cons
    unsigned short* cbase = (unsigned short*)(smem + 35016);
    // per consumer wave: sact 16x72=1152, sxk1 16x40=640, sx0 40 (=1832 ush)

    // ---- cooperative staging ----
    {
        const float4* s = (const float4*)seqw1T;   // w1T|w2T|whh260 contiguous
        float4* d = (float4*)smem;
        for (int i = tid; i < 8512; i += 192) d[i] = s[i];
        for (int i = tid; i < 128; i += 192) {
            tl[i] = times[b * Tn + i];
            ml[i] = mask[b * Tn + i];
        }
        if (tid < 3) flg[tid] = 0;
    }

    const float bi0 = bi[0];
    const float idn = invd[0];
    const float wic = Wi[lane];      // wave 2 nll weights

    // ---- producer state ----
    float w0c[2][32], w0tc[2], b0c[2], b1c[2], b2c[2], ftsc[2], ftsh[2];
    float wih0[4], gcr[4];
    float h = 0.f, c_ = 0.f;
    if (w == 0) {
        #pragma unroll
        for (int l = 0; l < 2; l++) {
            #pragma unroll
            for (int kk = 0; kk < 32; kk++)
                w0c[l][kk] = fW0[(l * 65 + 32 * l + kk) * 64 + lane];
            w0tc[l] = fW0[(l * 65 + 64) * 64 + lane];
            b0c[l]  = fb0[l * 64 + lane];
            b1c[l]  = fb1[l * 64 + lane];
            const int act = 32 * (1 - l);
            b2c[l]  = fb2[l * 128 + act + (lane & 31) + 64 * (lane >> 5)];
            ftsc[l] = ftw[l * 128 + lane];
            ftsh[l] = ftw[l * 128 + 64 + lane];
        }
        #pragma unroll
        for (int r = 0; r < 4; r++) {
            wih0[r] = W_ih[(r * 64 + lane) * 65];
            gcr[r]  = gc[b * 256 + r * 64 + lane];
        }
    }
    // ---- consumer state ----
    const int cw = w - 1;
    unsigned short* myact = cbase + cw * 1832;
    unsigned short* myxk  = myact + 1152;
    unsigned short* myx0  = myxk + 640;
    const int mc  = cw * 16 + l15;
    const bool valmc = (w > 0) && (mc < MCn);
    float wacc = 0.f;                // wave1/wave2: MC integral partial
    float nllc = 0.f;                // wave2 only

    __syncthreads();   // staging + flag init visible

    if (w == 0) {
        // ======================= PRODUCER (lean) ==========================
        for (int t = 0; t < Tn; t++) {
            if (t >= 3) {
                const unsigned need = (unsigned)(t - 2);
                while (flg[1] < need || flg[2] < need) __builtin_amdgcn_s_sleep(1);
                __threadfence_block();
            }
            hbuf[(t & 3) * 64 + lane] = h;
            if (lane == 0) flg[0] = (unsigned)(t + 1);   // DS in-order: data precedes flag
            const float tb = tl[t];
            float tscv[2], tshv[2];
            #pragma unroll
            for (int l = 0; l < 2; l++) {
                tscv[l] = tanhf_(tb * ftsc[l]);
                tshv[l] = tanhf_(tb * ftsh[l]);
            }
            float x = h;
            xl[lane] = x;
            #pragma unroll
            for (int l = 0; l < 2; l++) {
                const int kb  = 32 * l;
                const int act = 32 * (1 - l);
                {   // mv1: register weights
                    float p0 = b0c[l] + tb * w0tc[l], p1 = 0.f, p2 = 0.f, p3 = 0.f;
                    const float4* xv4 = (const float4*)(xl + kb);
                    #pragma unroll
                    for (int k4 = 0; k4 < 8; k4++) {
                        float4 xv = xv4[k4];
                        p0 += xv.x * w0c[l][4 * k4 + 0];
                        p1 += xv.y * w0c[l][4 * k4 + 1];
                        p2 += xv.z * w0c[l][4 * k4 + 2];
                        p3 += xv.w * w0c[l][4 * k4 + 3];
                    }
                    al[lane] = tanhf_((p0 + p1) + (p2 + p3));
                }
                {   // mv2: LDS weight stream
                    float p0 = b1c[l], p1 = 0.f, p2 = 0.f, p3 = 0.f;
                    const float4* av4 = (const float4*)al;
                    const float*  wp  = w1l + (l * 64 + lane) * 68;
                    #pragma unroll
                    for (int k4 = 0; k4 < 16; k4++) {
                        float4 av = av4[k4];
                        float4 wv = *(const float4*)(wp + 4 * k4);
                        p0 += av.x * wv.x; p1 += av.y * wv.y;
                        p2 += av.z * wv.z; p3 += av.w * wv.w;
                    }
                    al[lane] = tanhf_((p0 + p1) + (p2 + p3));
                }
                {   // mv3: LDS weight stream
                    float p0 = b2c[l], p1 = 0.f, p2 = 0.f, p3 = 0.f;
                    const float4* av4 = (const float4*)al;
                    const float*  wp  = w2l + (l * 64 + lane) * 68;
                    #pragma unroll
                    for (int k4 = 0; k4 < 16; k4++) {
                        float4 av = av4[k4];
                        float4 wv = *(const float4*)(wp + 4 * k4);
                        p0 += av.x * wv.x; p1 += av.y * wv.y;
                        p2 += av.z * wv.z; p3 += av.w * wv.w;
                    }
                    ssl[lane] = (p0 + p1) + (p2 + p3);
                }
                const int idx = (lane - act) & 31;
                const float scl = ssl[idx];
                const float shf = ssl[idx + 32];
                const float xa  = x * __expf(scl * tscv[l]) + shf * tshv[l];
                const bool active = (l == 0) ? (lane >= 32) : (lane < 32);
                x = active ? xa : x;
                xl[lane] = x;
            }
            h2buf[(t & 3) * 64 + lane] = x;    // h2 -> ring (flushed by wave 1)
            // LSTM
            float g0 = gcr[0] + tb * wih0[0];
            float g1 = gcr[1] + tb * wih0[1];
            float g2 = gcr[2] + tb * wih0[2];
            float g3 = gcr[3] + tb * wih0[3];
            {
                const float*  wr_base = whhl + lane * 260;
                const float4* hv4 = (const float4*)xl;
                #pragma unroll
                for (int k4 = 0; k4 < 16; k4++) {
                    float4 hv = hv4[k4];
                    const float* wr = wr_base + 16 * k4;
                    float4 wa = *(const float4*)(wr);
                    float4 wb = *(const float4*)(wr + 4);
                    float4 wc = *(const float4*)(wr + 8);
                    float4 wd = *(const float4*)(wr + 12);
                    g0 += hv.x * wa.x; g1 += hv.x * wa.y; g2 += hv.x * wa.z; g3 += hv.x * wa.w;
                    g0 += hv.y * wb.x; g1 += hv.y * wb.y; g2 += hv.y * wb.z; g3 += hv.y * wb.w;
                    g0 += hv.z * wc.x; g1 += hv.z * wc.y; g2 += hv.z * wc.z; g3 += hv.z * wc.w;
                    g0 += hv.w * wd.x; g1 += hv.w * wd.y; g2 += hv.w * wd.z; g3 += hv.w * wd.w;
                }
            }
            c_ = sigmoidf_(g1) * c_ + sigmoidf_(g0) * tanhf_(g2);
            h  = sigmoidf_(g3) * tanhf_(c_);
        }
        if (lane == 0) flg[0] = (unsigned)(Tn + 1);   // h2(Tn-1) available
    } else {
        // ======================= CONSUMERS ==========================
        for (int t = 0; t < Tn; t++) {
            while (flg[0] < (unsigned)(t + 1)) __builtin_amdgcn_s_sleep(1);
            __threadfence_block();
            // offloaded h2 flush / nll for step t-1
            if (t > 0) {
                const int pt = t - 1;
                const float h2v = h2buf[(pt & 3) * 64 + lane];
                if (cw == 0) {
                    out[1 + (b * Tn + pt) * 64 + lane] = h2v;
                } else {
                    float v = h2v * wic;
                    #pragma unroll
                    for (int off = 32; off >= 1; off >>= 1) v += __shfl_xor(v, off, 64);
                    nllc += -__logf(softplusf_(v + bi0)) * ml[pt];
                }
            }
            const float tb = tl[t];
            const float ts   = valmc ? u[t * MCn + mc] * tb : 0.f;
            const float sclf = valmc ? tb * (1.0f / 30.0f) * idn * ml[t] : 0.f;
            const float* hb  = hbuf + (t & 3) * 64;
            f32x4 xr[4];
            #pragma unroll
            for (int mt = 0; mt < 4; mt++)
                xr[mt] = *(const f32x4*)(hb + mt * 16 + quad * 4);
            if (lane < 32) myx0[lane] = f2b(hb[lane]);
            #pragma unroll
            for (int l = 0; l < 2; l++) {
                const unsigned short* wA1 = parwb + l * 2560;
                const unsigned short* wA2 = parwb + 5120 + l * 4608;
                const unsigned short* wA3 = parwb + 14336 + l * 4608;
                // mv1: K=32
                f32x4 c1[4];
                {
                    bf16x8 bfin = (l == 0) ? *(const bf16x8*)(myx0 + quad * 8)
                                           : *(const bf16x8*)(myxk + l15 * 40 + quad * 8);
                    #pragma unroll
                    for (int mt = 0; mt < 4; mt++) {
                        bf16x8 af = *(const bf16x8*)(wA1 + (mt * 16 + l15) * 40 + quad * 8);
                        f32x4 z = {0.f, 0.f, 0.f, 0.f};
                        c1[mt] = __builtin_amdgcn_mfma_f32_16x16x32_bf16(af, bfin, z, 0, 0, 0);
                    }
                }
                #pragma unroll
                for (int mt = 0; mt < 4; mt++) {
                    f32x4 b0r = *(const f32x4*)(parv + 0   + l * 64 + mt * 16 + quad * 4);
                    f32x4 w0r = *(const f32x4*)(parv + 128 + l * 64 + mt * 16 + quad * 4);
                    float v0 = tanhf_(c1[mt][0] + b0r[0] + ts * w0r[0]);
                    float v1 = tanhf_(c1[mt][1] + b0r[1] + ts * w0r[1]);
                    float v2 = tanhf_(c1[mt][2] + b0r[2] + ts * w0r[2]);
                    float v3 = tanhf_(c1[mt][3] + b0r[3] + ts * w0r[3]);
                    uint2 pk; pk.x = pk2(v0, v1); pk.y = pk2(v2, v3);
                    *(uint2*)(myact + l15 * 72 + mt * 16 + quad * 4) = pk;
                }
                // mv2: K=64
                f32x4 cc[4];
                #pragma unroll
                for (int mt = 0; mt < 4; mt++) cc[mt] = (f32x4){0.f, 0.f, 0.f, 0.f};
                #pragma unroll
                for (int kt = 0; kt < 2; kt++) {
                    bf16x8 bfa = *(const bf16x8*)(myact + l15 * 72 + kt * 32 + quad * 8);
                    #pragma unroll
                    for (int mt = 0; mt < 4; mt++) {
                        bf16x8 af = *(const bf16x8*)(wA2 + (mt * 16 + l15) * 72 + kt * 32 + quad * 8);
                        cc[mt] = __builtin_amdgcn_mfma_f32_16x16x32_bf16(af, bfa, cc[mt], 0, 0, 0);
                    }
                }
                #pragma unroll
                for (int mt = 0; mt < 4; mt++) {
                    f32x4 b1r = *(const f32x4*)(parv + 256 + l * 64 + mt * 16 + quad * 4);
                    float v0 = tanhf_(cc[mt][0] + b1r[0]);
                    float v1 = tanhf_(cc[mt][1] + b1r[1]);
                    float v2 = tanhf_(cc[mt][2] + b1r[2]);
                    float v3 = tanhf_(cc[mt][3] + b1r[3]);
                    uint2 pk; pk.x = pk2(v0, v1); pk.y = pk2(v2, v3);
                    *(uint2*)(myact + l15 * 72 + mt * 16 + quad * 4) = pk;
                }
                // mv3: K=64
                f32x4 ssf[4];
                #pragma unroll
                for (int mt = 0; mt < 4; mt++) ssf[mt] = (f32x4){0.f, 0.f, 0.f, 0.f};
                #pragma unroll
                for (int kt = 0; kt < 2; kt++) {
                    bf16x8 bfa = *(const bf16x8*)(myact + l15 * 72 + kt * 32 + quad * 8);
                    #pragma unroll
                    for (int mt = 0; mt < 4; mt++) {
                        bf16x8 af = *(const bf16x8*)(wA3 + (mt * 16 + l15) * 72 + kt * 32 + quad * 8);
                        ssf[mt] = __builtin_amdgcn_mfma_f32_16x16x32_bf16(af, bfa, ssf[mt], 0, 0, 0);
                    }
                }
                // coupling
                #pragma unroll
                for (int mt2 = 0; mt2 < 2; mt2++) {
                    f32x4 b2s = *(const f32x4*)(parv + 384 + l * 64 +      mt2 * 16 + quad * 4);
                    f32x4 b2h = *(const f32x4*)(parv + 384 + l * 64 + 32 + mt2 * 16 + quad * 4);
                    f32x4 fa  = *(const f32x4*)(parv + 512 + l * 32 + mt2 * 16 + quad * 4);
                    f32x4 fb  = *(const f32x4*)(parv + 576 + l * 32 + mt2 * 16 + quad * 4);
                    const int xm = (l == 0) ? (mt2 + 2) : mt2;
                    #pragma unroll
                    for (int r = 0; r < 4; r++) {
                        float sc  = ssf[mt2][r] + b2s[r];
                        float sh  = ssf[mt2 + 2][r] + b2h[r];
                        float tsc = tanhf_(ts * fa[r]);
                        float tsh = tanhf_(ts * fb[r]);
                        xr[xm][r] = xr[xm][r] * __expf(sc * tsc) + sh * tsh;
                    }
                    if (l == 0) {
                        uint2 pk;
                        pk.x = pk2(xr[xm][0], xr[xm][1]);
                        pk.y = pk2(xr[xm][2], xr[xm][3]);
                        *(uint2*)(myxk + l15 * 40 + mt2 * 16 + quad * 4) = pk;
                    }
                }
            }
            // intensity + integral accumulation
            float d0 = 0.f, d1 = 0.f;
            #pragma unroll
            for (int mt = 0; mt < 4; mt++) {
                f32x4 wi4 = *(const f32x4*)(parv + 640 + mt * 16 + quad * 4);
                d0 += xr[mt][0] * wi4[0] + xr[mt][2] * wi4[2];
                d1 += xr[mt][1] * wi4[1] + xr[mt][3] * wi4[3];
            }
            float d = d0 + d1;
            d += __shfl_xor(d, 16, 64);
            d += __shfl_xor(d, 32, 64);
            if (quad == 0) wacc += softplusf_(d + bi0) * sclf;
            // done flag: all this wave's ring reads precede (DS in-order)
            if (lane == 0) flg[w] = (unsigned)(t + 1);
        }
        // final h2 flush / nll (pt = Tn-1)
        while (flg[0] < (unsigned)(Tn + 1)) __builtin_amdgcn_s_sleep(1);
        __threadfence_block();
        {
            const int pt = Tn - 1;
            const float h2v = h2buf[(pt & 3) * 64 + lane];
            if (cw == 0) {
                out[1 + (b * Tn + pt) * 64 + lane] = h2v;
            } else {
                float v = h2v * wic;
                #pragma unroll
                for (int off = 32; off >= 1; off >>= 1) v += __shfl_xor(v, off, 64);
                nllc += -__logf(softplusf_(v + bi0)) * ml[pt];
            }
        }
    }

    // ---- block-level loss reduction ----
    if (w == 0) {
        if (lane == 0) pr[0] = 0.f;
    } else {
        #pragma unroll
        for (int off = 1; off <= 32; off <<= 1) wacc += __shfl_xor(wacc, off, 64);
        if (lane == 0) pr[w] = wacc + ((cw == 1) ? nllc * idn : 0.f);
    }
    __syncthreads();
    if (tid == 0) atomicAdd(out, pr[0] + pr[1] + pr[2]);
}

// ---------------------------------------------------------------------------
extern "C" void kernel_launch(void* const* d_in, const int* in_sizes, int n_in,
                              void* d_out, int out_size, void* d_ws, size_t ws_size,
                              hipStream_t stream)
{
    const float* times = (const float*)d_in[0];
    const int*   marks = (const int*)  d_in[1];
    const float* mask  = (const float*)d_in[2];
    const float* u     = (const float*)d_in[3];
    const float* emb   = (const float*)d_in[4];
    const float* fW0   = (const float*)d_in[5];
    const float* fb0   = (const float*)d_in[6];
    const float* fW1   = (const float*)d_in[7];
    const float* fb1   = (const float*)d_in[8];
    const float* fW2   = (const float*)d_in[9];
    const float* fb2   = (const float*)d_in[10];
    const float* ftw   = (const float*)d_in[11];
    const float* Wi    = (const float*)d_in[12];
    const float* bi    = (const float*)d_in[13];
    const float* W_ih  = (const float*)d_in[14];
    const float* W_hh  = (const float*)d_in[15];
    const float* b_ih  = (const float*)d_in[16];
    const float* b_hh  = (const float*)d_in[17];
    float* out = (float*)d_out;

    float* wsp     = (float*)d_ws;
    float* gc      = wsp;                   // 65,536
    float* invd    = gc + 65536;            // 4
    float* seqw1T  = invd + 4;              // 8,704  (w1T|w2T|whh260 contiguous)
    float* seqw2T  = seqw1T + 8704;         // 8,704
    float* whh260  = seqw2T + 8704;         // 16,640
    float* parv    = whh260 + 16640;        // 768
    unsigned short* parwb = (unsigned short*)(parv + 768);   // 23,552 ush

    hipMemsetAsync(d_out, 0, sizeof(float), stream);

    const int FUSED_SMEM = 35016 * 4 + 7328;   // 147,392 B (< 160 KiB)
    hipFuncSetAttribute((const void*)fused_kernel,
                        hipFuncAttributeMaxDynamicSharedMemorySize, FUSED_SMEM);

    prep_kernel<<<Bn + 8, 256, 0, stream>>>(marks, mask, emb, fW0, fW1, fW2,
                                            fb0, fb1, fb2, ftw, Wi, W_ih, W_hh,
                                            b_ih, b_hh, gc, invd, parv, parwb,
                                            seqw1T, seqw2T, whh260);
    fused_kernel<<<Bn, 192, FUSED_SMEM, stream>>>(times, mask, u, fW0, fb0,
                                                  fb1, fb2, ftw, Wi, bi, W_ih,
                                                  gc, seqw1T, parv, parwb,
                                                  invd, out);
}

// Round 17
// 581.365 us; speedup vs baseline: 1.0530x; 1.0530x over previous
//
#include <hip/hip_runtime.h>
#include <hip/hip_bf16.h>
#include <math.h>

#define Bn   256
#define Tn   128
#define HID  64
#define MCn  30

typedef __attribute__((ext_vector_type(8))) short bf16x8;
typedef __attribute__((ext_vector_type(4))) float f32x4;

// ---------------------------------------------------------------------------
__device__ __forceinline__ float rcp_(float x) { return __builtin_amdgcn_rcpf(x); }
__device__ __forceinline__ float tanhf_(float x) {
    float e = __expf(-2.0f * x);
    return __builtin_fmaf(2.0f, rcp_(1.0f + e), -1.0f);
}
__device__ __forceinline__ float sigmoidf_(float x) {
    return rcp_(1.0f + __expf(-x));
}
__device__ __forceinline__ float softplusf_(float z) {
    float e = __expf(-fabsf(z));
    return fmaxf(z, 0.0f) + __logf(1.0f + e);
}
__device__ __forceinline__ unsigned short f2b(float f) {
    union { float f; unsigned u; } v; v.f = f;
    unsigned r = v.u + 0x7FFF + ((v.u >> 16) & 1);
    return (unsigned short)(r >> 16);
}
__device__ __forceinline__ unsigned pk2(float a, float b) {
    union { __hip_bfloat162 h2; unsigned u; } cv;
    cv.h2 = __float22bfloat162_rn(make_float2(a, b));
    return cv.u;
}

// ws images (unchanged from r11)
extern "C" __global__ __launch_bounds__(256)
void prep_kernel(const int* __restrict__ marks, const float* __restrict__ mask,
                 const float* __restrict__ emb, const float* __restrict__ fW0,
                 const float* __restrict__ fW1, const float* __restrict__ fW2,
                 const float* __restrict__ fb0, const float* __restrict__ fb1,
                 const float* __restrict__ fb2, const float* __restrict__ ftw,
                 const float* __restrict__ Wi, const float* __restrict__ W_ih,
                 const float* __restrict__ W_hh,
                 const float* __restrict__ b_ih, const float* __restrict__ b_hh,
                 float* __restrict__ gc, float* __restrict__ invd,
                 float* __restrict__ parv, unsigned short* __restrict__ parwb,
                 float* __restrict__ seqw1T, float* __restrict__ seqw2T,
                 float* __restrict__ whh260)
{
    __shared__ float red[4];
    const int blk = blockIdx.x, tid = threadIdx.x;
    if (blk < Bn) {
        const int mark = marks[blk * Tn + 1];
        const float* er = emb + mark * HID;
        const float* wr = W_ih + tid * 65 + 1;
        float acc = b_ih[tid] + b_hh[tid];
        #pragma unroll
        for (int k = 0; k < HID; k++) acc += er[k] * wr[k];
        gc[blk * 256 + tid] = acc;
    } else if (blk == Bn) {
        float s = 0.f;
        for (int i = tid; i < Bn * Tn; i += 256) s += mask[i];
        #pragma unroll
        for (int off = 32; off >= 1; off >>= 1) s += __shfl_xor(s, off, 64);
        if ((tid & 63) == 0) red[tid >> 6] = s;
        __syncthreads();
        if (tid == 0) invd[0] = 1.0f / (red[0] + red[1] + red[2] + red[3]);
    } else if (blk == Bn + 1) {
        if (tid < 128) {
            int l = tid >> 6, m = tid & 63;
            parv[tid]       = fb0[tid];
            parv[128 + tid] = fW0[(l * 65 + 64) * 64 + m];
            parv[256 + tid] = fb1[tid];
            int act = 32 * (1 - l);
            parv[384 + tid] = fb2[l * 128 + act + (m & 31) + 64 * (m >> 5)];
        }
        if (tid < 64) {
            int l = tid >> 5, i2 = tid & 31, act = 32 * (1 - l);
            parv[512 + tid] = ftw[l * 128 + act + i2];
            parv[576 + tid] = ftw[l * 128 + 64 + act + i2];
            parv[640 + tid] = Wi[tid];
            parv[704 + tid] = 0.f;
        }
    } else if (blk == Bn + 2) {
        for (int i = tid; i < 5120; i += 256) {
            int k = i % 40, m = (i / 40) & 63, l = i / 2560;
            float v = (k < 32) ? fW0[(l * 65 + 32 * l + k) * 64 + m] : 0.f;
            parwb[i] = f2b(v);
        }
    } else if (blk == Bn + 3) {
        for (int i = tid; i < 9216; i += 256) {
            int k = i % 72, m = (i / 72) & 63, l = i / 4608;
            float v = (k < 64) ? fW1[(l * 64 + k) * 64 + m] : 0.f;
            parwb[5120 + i] = f2b(v);
        }
    } else if (blk == Bn + 4) {
        for (int i = tid; i < 9216; i += 256) {
            int k = i % 72, m = (i / 72) & 63, l = i / 4608;
            int act = 32 * (1 - l);
            float v = (k < 64) ? fW2[(l * 64 + k) * 128 + act + (m & 31) + 64 * (m >> 5)] : 0.f;
            parwb[14336 + i] = f2b(v);
        }
    } else if (blk == Bn + 5) {
        for (int i = tid; i < 8704; i += 256) {
            int k = i % 68, j = (i / 68) & 63, l = i / 4352;
            seqw1T[i] = (k < 64) ? fW1[(l * 64 + k) * 64 + j] : 0.f;
        }
    } else if (blk == Bn + 6) {
        for (int i = tid; i < 8704; i += 256) {
            int k = i % 68, j = (i / 68) & 63, l = i / 4352;
            int act = 32 * (1 - l);
            seqw2T[i] = (k < 64) ?
                fW2[(l * 64 + k) * 128 + act + (j & 31) + 64 * (j >> 5)] : 0.f;
        }
    } else {
        for (int i = tid; i < 16640; i += 256) {
            int j = i / 260, rem = i % 260, k = rem >> 2, r = rem & 3;
            whh260[i] = (k < 64) ? W_hh[(r * 64 + j) * 64 + k] : 0.f;
        }
    }
}

// ---------------------------------------------------------------------------
// FUSED kernel, FLAG-SYNCED (r15 champion): r11 producer/consumer split, but
// the per-step __syncthreads is replaced by one-way LDS flag sync (producer
// bumps a step counter after writing hbuf; consumers spin+fence). Producer
// runs its r6 barrier-free pace; its global h2 store is never force-drained.
// Back-pressure: producer waits (rarely) for consumers to clear slot t-2.
extern "C" __global__ __launch_bounds__(192, 1)
void fused_kernel(const float* __restrict__ times, const float* __restrict__ mask,
                  const float* __restrict__ u,
                  const float* __restrict__ fW0, const float* __restrict__ fb0,
                  const float* __restrict__ fb1, const float* __restrict__ fb2,
                  const float* __restrict__ ftw, const float* __restrict__ Wi,
                  const float* __restrict__ bi, const float* __restrict__ W_ih,
                  const float* __restrict__ gc, const float* __restrict__ seqw1T,
                  const float* __restrict__ parv,
                  const unsigned short* __restrict__ parwb,
                  const float* __restrict__ invd, float* __restrict__ out)
{
    const int tid  = threadIdx.x;
    const int lane = tid & 63;
    const int w    = tid >> 6;       // 0=producer, 1..2=consumers
    const int b    = blockIdx.x;
    const int quad = lane >> 4, l15 = lane & 15;

    extern __shared__ float smem[];
    float* w1l  = smem;              //  8704 : w1T, stride 68
    float* w2l  = smem + 8704;       //  8704 : w2T, stride 68
    float* whhl = smem + 17408;      // 16640 : whh260
    float* tl   = smem + 34048;      //   128
    float* ml   = smem + 34176;      //   128
    float* xl   = smem + 34304;      //    64 (producer-private)
    float* al   = smem + 34368;      //    64
    float* ssl  = smem + 34432;      //    64
    float* hbuf = smem + 34496;      //   128 = 2 slots x 64
    float* pr   = smem + 34624;      //     4
    volatile unsigned* flg = (volatile unsigned*)(smem + 34628);  // [0]=prod,[1],[2]=cons
    unsigned short* cbase = (unsigned short*)(smem + 34632);
    // per consumer wave: sact 16x72=1152, sxk1 16x40=640, sx0 40 (=1832 ush)

    // ---- cooperative staging ----
    {
        const float4* s = (const float4*)seqw1T;   // w1T|w2T|whh260 contiguous
        float4* d = (float4*)smem;
        for (int i = tid; i < 8512; i += 192) d[i] = s[i];
        for (int i = tid; i < 128; i += 192) {
            tl[i] = times[b * Tn + i];
            ml[i] = mask[b * Tn + i];
        }
        if (tid < 3) flg[tid] = 0;
    }

    const float bi0 = bi[0];
    const float idn = invd[0];

    // ---- producer state ----
    float w0c[2][32], w0tc[2], b0c[2], b1c[2], b2c[2], ftsc[2], ftsh[2];
    float wih0[4], gcr[4], wij = 0.f;
    float h = 0.f, c_ = 0.f, nllacc = 0.f;
    if (w == 0) {
        #pragma unroll
        for (int l = 0; l < 2; l++) {
            #pragma unroll
            for (int kk = 0; kk < 32; kk++)
                w0c[l][kk] = fW0[(l * 65 + 32 * l + kk) * 64 + lane];
            w0tc[l] = fW0[(l * 65 + 64) * 64 + lane];
            b0c[l]  = fb0[l * 64 + lane];
            b1c[l]  = fb1[l * 64 + lane];
            const int act = 32 * (1 - l);
            b2c[l]  = fb2[l * 128 + act + (lane & 31) + 64 * (lane >> 5)];
            ftsc[l] = ftw[l * 128 + lane];
            ftsh[l] = ftw[l * 128 + 64 + lane];
        }
        wij = Wi[lane];
        #pragma unroll
        for (int r = 0; r < 4; r++) {
            wih0[r] = W_ih[(r * 64 + lane) * 65];
            gcr[r]  = gc[b * 256 + r * 64 + lane];
        }
    }
    // ---- consumer state ----
    const int cw = w - 1;
    unsigned short* myact = cbase + cw * 1832;
    unsigned short* myxk  = myact + 1152;
    unsigned short* myx0  = myxk + 640;
    const int mc  = cw * 16 + l15;
    const bool valmc = (w > 0) && (mc < MCn);
    float wacc = 0.f;

    __syncthreads();   // staging + flag init visible (the ONLY in-loop-free barrier)

    if (w == 0) {
        // ======================= PRODUCER ==========================
        for (int t = 0; t < Tn; t++) {
            // back-pressure: consumers must have finished step t-2
            if (t >= 2) {
                const unsigned need = (unsigned)(t - 1);
                while (flg[1] < need || flg[2] < need) __builtin_amdgcn_s_sleep(1);
                __threadfence_block();
            }
            hbuf[(t & 1) * 64 + lane] = h;
            if (lane == 0) flg[0] = (unsigned)(t + 1);   // DS in-order: data precedes flag
            const float tb = tl[t];
            float tscv[2], tshv[2];
            #pragma unroll
            for (int l = 0; l < 2; l++) {
                tscv[l] = tanhf_(tb * ftsc[l]);
                tshv[l] = tanhf_(tb * ftsh[l]);
            }
            float x = h;
            xl[lane] = x;
            #pragma unroll
            for (int l = 0; l < 2; l++) {
                const int kb  = 32 * l;
                const int act = 32 * (1 - l);
                {   // mv1: register weights
                    float p0 = b0c[l] + tb * w0tc[l], p1 = 0.f, p2 = 0.f, p3 = 0.f;
                    const float4* xv4 = (const float4*)(xl + kb);
                    #pragma unroll
                    for (int k4 = 0; k4 < 8; k4++) {
                        float4 xv = xv4[k4];
                        p0 += xv.x * w0c[l][4 * k4 + 0];
                        p1 += xv.y * w0c[l][4 * k4 + 1];
                        p2 += xv.z * w0c[l][4 * k4 + 2];
                        p3 += xv.w * w0c[l][4 * k4 + 3];
                    }
                    al[lane] = tanhf_((p0 + p1) + (p2 + p3));
                }
                {   // mv2: LDS weight stream
                    float p0 = b1c[l], p1 = 0.f, p2 = 0.f, p3 = 0.f;
                    const float4* av4 = (const float4*)al;
                    const float*  wp  = w1l + (l * 64 + lane) * 68;
                    #pragma unroll
                    for (int k4 = 0; k4 < 16; k4++) {
                        float4 av = av4[k4];
                        float4 wv = *(const float4*)(wp + 4 * k4);
                        p0 += av.x * wv.x; p1 += av.y * wv.y;
                        p2 += av.z * wv.z; p3 += av.w * wv.w;
                    }
                    al[lane] = tanhf_((p0 + p1) + (p2 + p3));
                }
                {   // mv3: LDS weight stream
                    float p0 = b2c[l], p1 = 0.f, p2 = 0.f, p3 = 0.f;
                    const float4* av4 = (const float4*)al;
                    const float*  wp  = w2l + (l * 64 + lane) * 68;
                    #pragma unroll
                    for (int k4 = 0; k4 < 16; k4++) {
                        float4 av = av4[k4];
                        float4 wv = *(const float4*)(wp + 4 * k4);
                        p0 += av.x * wv.x; p1 += av.y * wv.y;
                        p2 += av.z * wv.z; p3 += av.w * wv.w;
                    }
                    ssl[lane] = (p0 + p1) + (p2 + p3);
                }
                const int idx = (lane - act) & 31;
                const float scl = ssl[idx];
                const float shf = ssl[idx + 32];
                const float xa  = x * __expf(scl * tscv[l]) + shf * tshv[l];
                const bool active = (l == 0) ? (lane >= 32) : (lane < 32);
                x = active ? xa : x;
                xl[lane] = x;
            }
            out[1 + (b * Tn + t) * 64 + lane] = x;   // fire-and-forget (never drained)
            float v = x * wij;
            #pragma unroll
            for (int off = 32; off >= 1; off >>= 1) v += __shfl_xor(v, off, 64);
            nllacc += -__logf(softplusf_(v + bi0)) * ml[t];
            // LSTM
            float g0 = gcr[0] + tb * wih0[0];
            float g1 = gcr[1] + tb * wih0[1];
            float g2 = gcr[2] + tb * wih0[2];
            float g3 = gcr[3] + tb * wih0[3];
            {
                const float*  wr_base = whhl + lane * 260;
                const float4* hv4 = (const float4*)xl;
                #pragma unroll
                for (int k4 = 0; k4 < 16; k4++) {
                    float4 hv = hv4[k4];
                    const float* wr = wr_base + 16 * k4;
                    float4 wa = *(const float4*)(wr);
                    float4 wb = *(const float4*)(wr + 4);
                    float4 wc = *(const float4*)(wr + 8);
                    float4 wd = *(const float4*)(wr + 12);
                    g0 += hv.x * wa.x; g1 += hv.x * wa.y; g2 += hv.x * wa.z; g3 += hv.x * wa.w;
                    g0 += hv.y * wb.x; g1 += hv.y * wb.y; g2 += hv.y * wb.z; g3 += hv.y * wb.w;
                    g0 += hv.z * wc.x; g1 += hv.z * wc.y; g2 += hv.z * wc.z; g3 += hv.z * wc.w;
                    g0 += hv.w * wd.x; g1 += hv.w * wd.y; g2 += hv.w * wd.z; g3 += hv.w * wd.w;
                }
            }
            c_ = sigmoidf_(g1) * c_ + sigmoidf_(g0) * tanhf_(g2);
            h  = sigmoidf_(g3) * tanhf_(c_);
        }
    } else {
        // ======================= CONSUMERS ==========================
        for (int t = 0; t < Tn; t++) {
            while (flg[0] < (unsigned)(t + 1)) __builtin_amdgcn_s_sleep(1);
            __threadfence_block();
            const float tb = tl[t];
            const float ts   = valmc ? u[t * MCn + mc] * tb : 0.f;
            const float sclf = valmc ? tb * (1.0f / 30.0f) * idn * ml[t] : 0.f;
            const float* hb  = hbuf + (t & 1) * 64;
            f32x4 xr[4];
            #pragma unroll
            for (int mt = 0; mt < 4; mt++)
                xr[mt] = *(const f32x4*)(hb + mt * 16 + quad * 4);
            if (lane < 32) myx0[lane] = f2b(hb[lane]);
            #pragma unroll
            for (int l = 0; l < 2; l++) {
                const unsigned short* wA1 = parwb + l * 2560;
                const unsigned short* wA2 = parwb + 5120 + l * 4608;
                const unsigned short* wA3 = parwb + 14336 + l * 4608;
                // mv1: K=32
                f32x4 c1[4];
                {
                    bf16x8 bfin = (l == 0) ? *(const bf16x8*)(myx0 + quad * 8)
                                           : *(const bf16x8*)(myxk + l15 * 40 + quad * 8);
                    #pragma unroll
                    for (int mt = 0; mt < 4; mt++) {
                        bf16x8 af = *(const bf16x8*)(wA1 + (mt * 16 + l15) * 40 + quad * 8);
                        f32x4 z = {0.f, 0.f, 0.f, 0.f};
                        c1[mt] = __builtin_amdgcn_mfma_f32_16x16x32_bf16(af, bfin, z, 0, 0, 0);
                    }
                }
                #pragma unroll
                for (int mt = 0; mt < 4; mt++) {
                    f32x4 b0r = *(const f32x4*)(parv + 0   + l * 64 + mt * 16 + quad * 4);
                    f32x4 w0r = *(const f32x4*)(parv + 128 + l * 64 + mt * 16 + quad * 4);
                    float v0 = tanhf_(c1[mt][0] + b0r[0] + ts * w0r[0]);
                    float v1 = tanhf_(c1[mt][1] + b0r[1] + ts * w0r[1]);
                    float v2 = tanhf_(c1[mt][2] + b0r[2] + ts * w0r[2]);
                    float v3 = tanhf_(c1[mt][3] + b0r[3] + ts * w0r[3]);
                    uint2 pk; pk.x = pk2(v0, v1); pk.y = pk2(v2, v3);
                    *(uint2*)(myact + l15 * 72 + mt * 16 + quad * 4) = pk;
                }
                // mv2: K=64
                f32x4 cc[4];
                #pragma unroll
                for (int mt = 0; mt < 4; mt++) cc[mt] = (f32x4){0.f, 0.f, 0.f, 0.f};
                #pragma unroll
                for (int kt = 0; kt < 2; kt++) {
                    bf16x8 bfa = *(const bf16x8*)(myact + l15 * 72 + kt * 32 + quad * 8);
                    #pragma unroll
                    for (int mt = 0; mt < 4; mt++) {
                        bf16x8 af = *(const bf16x8*)(wA2 + (mt * 16 + l15) * 72 + kt * 32 + quad * 8);
                        cc[mt] = __builtin_amdgcn_mfma_f32_16x16x32_bf16(af, bfa, cc[mt], 0, 0, 0);
                    }
                }
                #pragma unroll
                for (int mt = 0; mt < 4; mt++) {
                    f32x4 b1r = *(const f32x4*)(parv + 256 + l * 64 + mt * 16 + quad * 4);
                    float v0 = tanhf_(cc[mt][0] + b1r[0]);
                    float v1 = tanhf_(cc[mt][1] + b1r[1]);
                    float v2 = tanhf_(cc[mt][2] + b1r[2]);
                    float v3 = tanhf_(cc[mt][3] + b1r[3]);
                    uint2 pk; pk.x = pk2(v0, v1); pk.y = pk2(v2, v3);
                    *(uint2*)(myact + l15 * 72 + mt * 16 + quad * 4) = pk;
                }
                // mv3: K=64
                f32x4 ssf[4];
                #pragma unroll
                for (int mt = 0; mt < 4; mt++) ssf[mt] = (f32x4){0.f, 0.f, 0.f, 0.f};
                #pragma unroll
                for (int kt = 0; kt < 2; kt++) {
                    bf16x8 bfa = *(const bf16x8*)(myact + l15 * 72 + kt * 32 + quad * 8);
                    #pragma unroll
                    for (int mt = 0; mt < 4; mt++) {
                        bf16x8 af = *(const bf16x8*)(wA3 + (mt * 16 + l15) * 72 + kt * 32 + quad * 8);
                        ssf[mt] = __builtin_amdgcn_mfma_f32_16x16x32_bf16(af, bfa, ssf[mt], 0, 0, 0);
                    }
                }
                // coupling
                #pragma unroll
                for (int mt2 = 0; mt2 < 2; mt2++) {
                    f32x4 b2s = *(const f32x4*)(parv + 384 + l * 64 +      mt2 * 16 + quad * 4);
                    f32x4 b2h = *(const f32x4*)(parv + 384 + l * 64 + 32 + mt2 * 16 + quad * 4);
                    f32x4 fa  = *(const f32x4*)(parv + 512 + l * 32 + mt2 * 16 + quad * 4);
                    f32x4 fb  = *(const f32x4*)(parv + 576 + l * 32 + mt2 * 16 + quad * 4);
                    const int xm = (l == 0) ? (mt2 + 2) : mt2;
                    #pragma unroll
                    for (int r = 0; r < 4; r++) {
                        float sc  = ssf[mt2][r] + b2s[r];
                        float sh  = ssf[mt2 + 2][r] + b2h[r];
                        float tsc = tanhf_(ts * fa[r]);
                        float tsh = tanhf_(ts * fb[r]);
                        xr[xm][r] = xr[xm][r] * __expf(sc * tsc) + sh * tsh;
                    }
                    if (l == 0) {
                        uint2 pk;
                        pk.x = pk2(xr[xm][0], xr[xm][1]);
                        pk.y = pk2(xr[xm][2], xr[xm][3]);
                        *(uint2*)(myxk + l15 * 40 + mt2 * 16 + quad * 4) = pk;
                    }
                }
            }
            // intensity + loss
            float d0 = 0.f, d1 = 0.f;
            #pragma unroll
            for (int mt = 0; mt < 4; mt++) {
                f32x4 wi4 = *(const f32x4*)(parv + 640 + mt * 16 + quad * 4);
                d0 += xr[mt][0] * wi4[0] + xr[mt][2] * wi4[2];
                d1 += xr[mt][1] * wi4[1] + xr[mt][3] * wi4[3];
            }
            float d = d0 + d1;
            d += __shfl_xor(d, 16, 64);
            d += __shfl_xor(d, 32, 64);
            if (quad == 0) wacc += softplusf_(d + bi0) * sclf;
            // done flag: all this wave's hbuf reads precede (DS in-order)
            if (lane == 0) flg[w] = (unsigned)(t + 1);
        }
    }

    // ---- block-level loss reduction ----
    if (w == 0) {
        if (lane == 0) pr[0] = nllacc * idn;
    } else {
        #pragma unroll
        for (int off = 1; off <= 32; off <<= 1) wacc += __shfl_xor(wacc, off, 64);
        if (lane == 0) pr[w] = wacc;
    }
    __syncthreads();
    if (tid == 0) atomicAdd(out, pr[0] + pr[1] + pr[2]);
}

// ---------------------------------------------------------------------------
extern "C" void kernel_launch(void* const* d_in, const int* in_sizes, int n_in,
                              void* d_out, int out_size, void* d_ws, size_t ws_size,
                              hipStream_t stream)
{
    const float* times = (const float*)d_in[0];
    const int*   marks = (const int*)  d_in[1];
    const float* mask  = (const float*)d_in[2];
    const float* u     = (const float*)d_in[3];
    const float* emb   = (const float*)d_in[4];
    const float* fW0   = (const float*)d_in[5];
    const float* fb0   = (const float*)d_in[6];
    const float* fW1   = (const float*)d_in[7];
    const float* fb1   = (const float*)d_in[8];
    const float* fW2   = (const float*)d_in[9];
    const float* fb2   = (const float*)d_in[10];
    const float* ftw   = (const float*)d_in[11];
    const float* Wi    = (const float*)d_in[12];
    const float* bi    = (const float*)d_in[13];
    const float* W_ih  = (const float*)d_in[14];
    const float* W_hh  = (const float*)d_in[15];
    const float* b_ih  = (const float*)d_in[16];
    const float* b_hh  = (const float*)d_in[17];
    float* out = (float*)d_out;

    float* wsp     = (float*)d_ws;
    float* gc      = wsp;                   // 65,536
    float* invd    = gc + 65536;            // 4
    float* seqw1T  = invd + 4;              // 8,704  (w1T|w2T|whh260 contiguous)
    float* seqw2T  = seqw1T + 8704;         // 8,704
    float* whh260  = seqw2T + 8704;         // 16,640
    float* parv    = whh260 + 16640;        // 768
    unsigned short* parwb = (unsigned short*)(parv + 768);   // 23,552 ush

    hipMemsetAsync(d_out, 0, sizeof(float), stream);

    const int FUSED_SMEM = 34632 * 4 + 7328;   // 145,856 B (< 160 KiB)
    hipFuncSetAttribute((const void*)fused_kernel,
                        hipFuncAttributeMaxDynamicSharedMemorySize, FUSED_SMEM);

    prep_kernel<<<Bn + 8, 256, 0, stream>>>(marks, mask, emb, fW0, fW1, fW2,
                                            fb0, fb1, fb2, ftw, Wi, W_ih, W_hh,
                                            b_ih, b_hh, gc, invd, parv, parwb,
                                            seqw1T, seqw2T, whh260);
    fused_kernel<<<Bn, 192, FUSED_SMEM, stream>>>(times, mask, u, fW0, fb0,
                                                  fb1, fb2, ftw, Wi, bi, W_ih,
                                                  gc, seqw1T, parv, parwb,
                                                  invd, out);
}